// Round 2
// baseline (179.335 us; speedup 1.0000x reference)
//
#include <hip/hip_runtime.h>

typedef unsigned short ushort_t;
typedef __bf16 bf16x8 __attribute__((ext_vector_type(8)));
typedef float f32x4 __attribute__((ext_vector_type(4)));
typedef float f32x2 __attribute__((ext_vector_type(2)));
typedef ushort_t us4 __attribute__((ext_vector_type(4)));

#define T_SOFT 32.0f
#define THRESH 0.76604444311897803f   // cos(40 deg)
#define SW 1048                       // W strip LDS row stride (bf16)

__device__ __forceinline__ ushort_t f2bf(float f) {
  union { float f; unsigned u; } x; x.f = f;
  unsigned r = (x.u + 0x7fffu + ((x.u >> 16) & 1u)) >> 16;  // RNE
  return (ushort_t)r;
}
__device__ __forceinline__ float bf2f(ushort_t h) {
  union { unsigned u; float f; } x; x.u = ((unsigned)h) << 16; return x.f;
}

// pack 4 fp32 -> 4 bf16
__device__ __forceinline__ us4 pack4(float4 x) {
  union { unsigned u[2]; us4 h; } r;
  union { float4 f; unsigned u[4]; } a;
  a.f = x;
  r.u[0] = __builtin_amdgcn_perm(a.u[1] + 0x8000u, a.u[0] + 0x8000u, 0x07060302u);
  r.u[1] = __builtin_amdgcn_perm(a.u[3] + 0x8000u, a.u[2] + 0x8000u, 0x07060302u);
  return r.h;
}

// ---------------- tr3: transposes + poutN left copy + zero fills ----------------
// grid 1433: [0,976) transposes, [976,1288) poutN cols 0..311, [1288,1432) zero img_h+pacc2, 1432 gn tail
__global__ __launch_bounds__(256) void tr3_k(const float* __restrict__ s0, ushort_t* __restrict__ d0,
                                             const float* __restrict__ s1, ushort_t* __restrict__ d1,
                                             const float* __restrict__ s2, ushort_t* __restrict__ d2,
                                             const float* __restrict__ attributes, ushort_t* __restrict__ poutN,
                                             ushort_t* __restrict__ gn_bf, float* __restrict__ zero_base) {
  int b = blockIdx.x, tid = threadIdx.x;
  if (b >= 976) {
    if (b < 1288) {            // poutN[j][0..311] = bf16(attributes[j][:]); rows 1000..1023 zero
      int t = (b - 976) * 256 + tid;       // 0..79871
      int row = t / 78, c4 = (t - row * 78) * 4;
      us4 v = {0, 0, 0, 0};
      if (row < 1000) v = pack4(*reinterpret_cast<const float4*>(attributes + (size_t)row * 312 + c4));
      *reinterpret_cast<us4*>(poutN + (size_t)row * 640 + c4) = v;
    } else if (b < 1432) {     // zero img_h (1MB) + pacc2 (1.25MB) contiguous span
      int t = (b - 1288) * 256 + tid;      // 0..36863
      float4* zp = reinterpret_cast<float4*>(zero_base) + (size_t)t * 4;
      float4 z = make_float4(0.f, 0.f, 0.f, 0.f);
      zp[0] = z; zp[1] = z; zp[2] = z; zp[3] = z;
    } else {                   // zero gn_bf rows 1000..1007
      us4 z = {0, 0, 0, 0};
      *reinterpret_cast<us4*>(gn_bf + 1000 * 128 + tid * 4) = z;
    }
    return;
  }
  __shared__ float tl[32][33];
  const float* src; ushort_t* dst; int R, C, Cw, Rpad, local, ctiles;
  if (b < 640)       { src = s0; dst = d0; R = 2048; C = 312; Cw = 320; Rpad = 2048; local = b;       ctiles = 10; }
  else if (b < 896)  { src = s1; dst = d1; R = 2048; C = 128; Cw = 128; Rpad = 2048; local = b - 640; ctiles = 4;  }
  else               { src = s2; dst = d2; R = 624;  C = 128; Cw = 128; Rpad = 640;  local = b - 896; ctiles = 4;  }
  int rt = local / ctiles, ct = local - rt * ctiles;
  int r0 = rt * 32, c0 = ct * 32;
  #pragma unroll
  for (int p = 0; p < 4; ++p) {
    int idx = p * 256 + tid;
    int rr = idx >> 5, cc = idx & 31;
    float v = 0.f;
    if (r0 + rr < R && c0 + cc < C) v = src[(size_t)(r0 + rr) * C + (c0 + cc)];
    tl[cc][rr] = v;
  }
  __syncthreads();
  int cc = tid >> 3, rq = tid & 7;
  if (c0 + cc < Cw) {
    us4 o;
    o[0] = f2bf(tl[cc][rq * 4 + 0]);
    o[1] = f2bf(tl[cc][rq * 4 + 1]);
    o[2] = f2bf(tl[cc][rq * 4 + 2]);
    o[3] = f2bf(tl[cc][rq * 4 + 3]);
    *reinterpret_cast<us4*>(dst + (size_t)(c0 + cc) * Rpad + r0 + rq * 4) = o;
  }
}

// ---------------- img_h GEMM block: split-K (256/chunk, 4 steps), atomic fp32 epilogue ----------------
__device__ __forceinline__ void gemm_imgh(const float* __restrict__ A, const ushort_t* __restrict__ BT,
                                          float* __restrict__ C, int r0, int k0,
                                          ushort_t* __restrict__ As, ushort_t* __restrict__ Bs, int tid) {
  const int SA = 72;
  int lane = tid & 63, wv = tid >> 6;
  int l15 = lane & 15, quad = lane >> 4;
  int arow = tid >> 4, akq = tid & 15;
  int brow = tid >> 3, bkq = tid & 7;
  const float* agp[8];
  #pragma unroll
  for (int p = 0; p < 8; ++p) agp[p] = A + (size_t)(r0 + arow + p * 16) * 2048 + k0 + akq * 4;
  const ushort_t* bgp[4];
  #pragma unroll
  for (int p = 0; p < 4; ++p) bgp[p] = BT + (size_t)(brow + p * 32) * 2048 + k0 + bkq * 8;

  float4 ap[8]; bf16x8 bp[4];
  #pragma unroll
  for (int p = 0; p < 8; ++p) ap[p] = *reinterpret_cast<const float4*>(agp[p]);
  #pragma unroll
  for (int p = 0; p < 4; ++p) bp[p] = *reinterpret_cast<const bf16x8*>(bgp[p]);

  f32x4 acc[2][8];
  #pragma unroll
  for (int i = 0; i < 2; ++i)
    #pragma unroll
    for (int j = 0; j < 8; ++j) acc[i][j] = f32x4{0.f, 0.f, 0.f, 0.f};

  for (int s = 0; s < 4; ++s) {
    if (s) __syncthreads();
    #pragma unroll
    for (int p = 0; p < 8; ++p)
      *reinterpret_cast<us4*>(As + (arow + p * 16) * SA + akq * 4) = pack4(ap[p]);
    #pragma unroll
    for (int p = 0; p < 4; ++p)
      *reinterpret_cast<bf16x8*>(Bs + (brow + p * 32) * SA + bkq * 8) = bp[p];
    if (s + 1 < 4) {
      #pragma unroll
      for (int p = 0; p < 8; ++p) ap[p] = *reinterpret_cast<const float4*>(agp[p] + 64);
      #pragma unroll
      for (int p = 0; p < 4; ++p) bp[p] = *reinterpret_cast<const bf16x8*>(bgp[p] + 64);
      #pragma unroll
      for (int p = 0; p < 8; ++p) agp[p] += 64;
      #pragma unroll
      for (int p = 0; p < 4; ++p) bgp[p] += 64;
    }
    __syncthreads();
    #pragma unroll
    for (int kh = 0; kh < 2; ++kh) {
      bf16x8 af[2];
      #pragma unroll
      for (int pi = 0; pi < 2; ++pi)
        af[pi] = *reinterpret_cast<bf16x8*>(As + ((wv * 2 + pi) * 16 + l15) * SA + kh * 32 + quad * 8);
      #pragma unroll
      for (int ct = 0; ct < 8; ++ct) {
        bf16x8 bfr = *reinterpret_cast<bf16x8*>(Bs + (ct * 16 + l15) * SA + kh * 32 + quad * 8);
        acc[0][ct] = __builtin_amdgcn_mfma_f32_16x16x32_bf16(af[0], bfr, acc[0][ct], 0, 0, 0);
        acc[1][ct] = __builtin_amdgcn_mfma_f32_16x16x32_bf16(af[1], bfr, acc[1][ct], 0, 0, 0);
      }
    }
  }
  #pragma unroll
  for (int pi = 0; pi < 2; ++pi)
    #pragma unroll
    for (int ct = 0; ct < 8; ++ct) {
      int col = ct * 16 + l15;
      #pragma unroll
      for (int r = 0; r < 4; ++r) {
        int row = r0 + (wv * 2 + pi) * 16 + quad * 4 + r;
        atomicAdd(&C[(size_t)row * 128 + col], acc[pi][ct][r]);
      }
    }
}

// ---------------- proto GEMM: pacc2[j][m] += img_proto[j][k]*slimT[m][k], split-K ----------------
__device__ __forceinline__ void gemm_proto(const float* __restrict__ A, const ushort_t* __restrict__ BT,
                                           float* __restrict__ pacc2, int r0, int c0, int k0,
                                           ushort_t* __restrict__ As, ushort_t* __restrict__ Bs, int tid) {
  const int SA = 72;
  int lane = tid & 63, wv = tid >> 6;
  int l15 = lane & 15, quad = lane >> 4;
  int arow = tid >> 4, akq = tid & 15;
  int brow = tid >> 3, bkq = tid & 7;
  const float* agp[8];
  #pragma unroll
  for (int p = 0; p < 8; ++p) {
    int r = r0 + arow + p * 16; if (r >= 1000) r = 999;
    agp[p] = A + (size_t)r * 2048 + k0 + akq * 4;
  }
  const ushort_t* bgp[4];
  #pragma unroll
  for (int p = 0; p < 4; ++p) {
    int n = c0 + brow + p * 32; if (n >= 320) n = 319;
    bgp[p] = BT + (size_t)n * 2048 + k0 + bkq * 8;
  }
  float4 ap[8]; bf16x8 bp[4];
  #pragma unroll
  for (int p = 0; p < 8; ++p) ap[p] = *reinterpret_cast<const float4*>(agp[p]);
  #pragma unroll
  for (int p = 0; p < 4; ++p) bp[p] = *reinterpret_cast<const bf16x8*>(bgp[p]);

  f32x4 acc[2][8];
  #pragma unroll
  for (int i = 0; i < 2; ++i)
    #pragma unroll
    for (int j = 0; j < 8; ++j) acc[i][j] = f32x4{0.f, 0.f, 0.f, 0.f};

  for (int s = 0; s < 4; ++s) {
    if (s) __syncthreads();
    #pragma unroll
    for (int p = 0; p < 8; ++p)
      *reinterpret_cast<us4*>(As + (arow + p * 16) * SA + akq * 4) = pack4(ap[p]);
    #pragma unroll
    for (int p = 0; p < 4; ++p)
      *reinterpret_cast<bf16x8*>(Bs + (brow + p * 32) * SA + bkq * 8) = bp[p];
    if (s + 1 < 4) {
      #pragma unroll
      for (int p = 0; p < 8; ++p) ap[p] = *reinterpret_cast<const float4*>(agp[p] + 64);
      #pragma unroll
      for (int p = 0; p < 4; ++p) bp[p] = *reinterpret_cast<const bf16x8*>(bgp[p] + 64);
      #pragma unroll
      for (int p = 0; p < 8; ++p) agp[p] += 64;
      #pragma unroll
      for (int p = 0; p < 4; ++p) bgp[p] += 64;
    }
    __syncthreads();
    #pragma unroll
    for (int kh = 0; kh < 2; ++kh) {
      bf16x8 af[2];
      #pragma unroll
      for (int pi = 0; pi < 2; ++pi)
        af[pi] = *reinterpret_cast<bf16x8*>(As + ((wv * 2 + pi) * 16 + l15) * SA + kh * 32 + quad * 8);
      #pragma unroll
      for (int ct = 0; ct < 8; ++ct) {
        bf16x8 bfr = *reinterpret_cast<bf16x8*>(Bs + (ct * 16 + l15) * SA + kh * 32 + quad * 8);
        acc[0][ct] = __builtin_amdgcn_mfma_f32_16x16x32_bf16(af[0], bfr, acc[0][ct], 0, 0, 0);
        acc[1][ct] = __builtin_amdgcn_mfma_f32_16x16x32_bf16(af[1], bfr, acc[1][ct], 0, 0, 0);
      }
    }
  }
  #pragma unroll
  for (int pi = 0; pi < 2; ++pi)
    #pragma unroll
    for (int ct = 0; ct < 8; ++ct) {
      int col = c0 + ct * 16 + l15;
      if (col < 320) {
        #pragma unroll
        for (int r = 0; r < 4; ++r) {
          int row = r0 + (wv * 2 + pi) * 16 + quad * 4 + r;
          atomicAdd(&pacc2[(size_t)row * 320 + col], acc[pi][ct][r]);
        }
      }
    }
}

// ---------------- mega: gn (125) + img_h splitK8 (128) + proto splitK8 (192) ----------------
__global__ __launch_bounds__(256) void mega_k(
    const float* __restrict__ attributes, const float* __restrict__ att_g,
    ushort_t* __restrict__ gn_bf,
    const float* __restrict__ img_proto, const ushort_t* __restrict__ slimT,
    const float* __restrict__ image_feats, const ushort_t* __restrict__ imgwT,
    float* __restrict__ img_h, float* __restrict__ pacc2) {
  __shared__ ushort_t As[128 * 72];
  __shared__ ushort_t Bs[128 * 72];
  int b = blockIdx.x, tid = threadIdx.x;
  if (b < 125) {
    __shared__ float a_lds[8][316];
    __shared__ float red2[8][2];
    int h = tid & 127;
    int c0 = b * 8;
    for (int idx = tid; idx < 8 * 312; idx += 256) {
      int r = idx / 312;
      int k = idx - r * 312;
      a_lds[r][k] = attributes[(c0 + r) * 312 + k];
    }
    __syncthreads();
    float acc[8] = {0.f,0.f,0.f,0.f,0.f,0.f,0.f,0.f};
    for (int k = 0; k < 312; k += 4) {
      float w0 = att_g[(k + 0) * 128 + h];
      float w1 = att_g[(k + 1) * 128 + h];
      float w2 = att_g[(k + 2) * 128 + h];
      float w3 = att_g[(k + 3) * 128 + h];
      #pragma unroll
      for (int r = 0; r < 8; ++r) {
        float4 a4 = *reinterpret_cast<const float4*>(&a_lds[r][k]);
        acc[r] += a4.x * w0 + a4.y * w1 + a4.z * w2 + a4.w * w3;
      }
    }
    int lane = tid & 63, wvid = (tid >> 6) & 1;
    #pragma unroll
    for (int r = 0; r < 8; ++r) {
      float v = acc[r] * acc[r];
      #pragma unroll
      for (int off = 32; off > 0; off >>= 1) v += __shfl_xor(v, off, 64);
      if (lane == 0) red2[r][wvid] = v;
    }
    __syncthreads();
    #pragma unroll
    for (int r = 0; r < 8; ++r) {
      float nrm = fmaxf(sqrtf(red2[r][0] + red2[r][1]), 1e-12f);
      gn_bf[(c0 + r) * 128 + h] = f2bf(acc[r] / nrm);
    }
    return;
  }
  b -= 125;
  if (b < 128) {
    int tile = b >> 3, kc = b & 7;
    gemm_imgh(image_feats, imgwT, img_h, tile * 128, kc * 256, As, Bs, tid);
  } else {
    b -= 128;
    int tile = b >> 3, kc = b & 7;
    int rb = tile / 3, cb = tile - rb * 3;
    gemm_proto(img_proto, slimT, pacc2, rb * 128, cb * 128, kc * 256, As, Bs, tid);
  }
}

// ---------------- conv: pacc2 fp32 [1024][320] -> poutN cols 312..639 bf16 (zeros past 631) ----------------
__global__ __launch_bounds__(256) void conv_k(const float* __restrict__ pacc2, ushort_t* __restrict__ poutN) {
  int t = blockIdx.x * 256 + threadIdx.x;   // 328*256 = 83968 = 1024*82
  int row = t / 82, m = (t - row * 82) * 4;
  us4 v = {0, 0, 0, 0};
  if (m < 320) v = pack4(*reinterpret_cast<const float4*>(pacc2 + (size_t)row * 320 + m));
  *reinterpret_cast<us4*>(poutN + (size_t)row * 640 + 312 + m) = v;
}

// ---------------- g_k: GT[128][1024] = protowT(128x640) @ poutN(1024x640)^T ; + biasG ----------------
__global__ __launch_bounds__(256) void g_k(const ushort_t* __restrict__ protowT, const ushort_t* __restrict__ poutN,
                                           const float* __restrict__ proto_w, const float* __restrict__ slim_b,
                                           const float* __restrict__ proto_b,
                                           ushort_t* __restrict__ GT, float* __restrict__ biasG) {
  int b = blockIdx.x, tid = threadIdx.x;
  if (b >= 8) {   // biasG[h] = proto_b[h] + sum_n slim_b[n]*proto_w[312+n][h]
    int h = tid & 127;
    float acc = proto_b[h];
    for (int n = 0; n < 312; n += 4) {
      acc += slim_b[n + 0] * proto_w[(size_t)(312 + n) * 128 + h];
      acc += slim_b[n + 1] * proto_w[(size_t)(313 + n) * 128 + h];
      acc += slim_b[n + 2] * proto_w[(size_t)(314 + n) * 128 + h];
      acc += slim_b[n + 3] * proto_w[(size_t)(315 + n) * 128 + h];
    }
    if (tid < 128) biasG[h] = acc;
    return;
  }
  const int SA = 72;
  __shared__ ushort_t As[128 * 72];
  __shared__ ushort_t Bs[128 * 72];
  int lane = tid & 63, wv = tid >> 6;
  int l15 = lane & 15, quad = lane >> 4;
  int hrow = tid >> 3, hkq = tid & 7;
  size_t j0 = (size_t)b * 128;
  const ushort_t* agp[4];
  const ushort_t* bgp[4];
  #pragma unroll
  for (int p = 0; p < 4; ++p) {
    agp[p] = protowT + (size_t)(hrow + p * 32) * 640 + hkq * 8;
    bgp[p] = poutN + (j0 + hrow + p * 32) * 640 + hkq * 8;
  }
  bf16x8 ar[4], br[4];
  #pragma unroll
  for (int p = 0; p < 4; ++p) { ar[p] = *reinterpret_cast<const bf16x8*>(agp[p]); br[p] = *reinterpret_cast<const bf16x8*>(bgp[p]); }

  f32x4 acc[2][8];
  #pragma unroll
  for (int i = 0; i < 2; ++i)
    #pragma unroll
    for (int j = 0; j < 8; ++j) acc[i][j] = f32x4{0.f, 0.f, 0.f, 0.f};

  for (int s = 0; s < 10; ++s) {
    if (s) __syncthreads();
    #pragma unroll
    for (int p = 0; p < 4; ++p) {
      *reinterpret_cast<bf16x8*>(As + (hrow + p * 32) * SA + hkq * 8) = ar[p];
      *reinterpret_cast<bf16x8*>(Bs + (hrow + p * 32) * SA + hkq * 8) = br[p];
    }
    if (s + 1 < 10) {
      #pragma unroll
      for (int p = 0; p < 4; ++p) {
        ar[p] = *reinterpret_cast<const bf16x8*>(agp[p] + 64);
        br[p] = *reinterpret_cast<const bf16x8*>(bgp[p] + 64);
        agp[p] += 64; bgp[p] += 64;
      }
    }
    __syncthreads();
    #pragma unroll
    for (int kh = 0; kh < 2; ++kh) {
      bf16x8 af[2];
      #pragma unroll
      for (int pi = 0; pi < 2; ++pi)
        af[pi] = *reinterpret_cast<bf16x8*>(As + ((wv * 2 + pi) * 16 + l15) * SA + kh * 32 + quad * 8);
      #pragma unroll
      for (int ct = 0; ct < 8; ++ct) {
        bf16x8 bfr = *reinterpret_cast<bf16x8*>(Bs + (ct * 16 + l15) * SA + kh * 32 + quad * 8);
        acc[0][ct] = __builtin_amdgcn_mfma_f32_16x16x32_bf16(af[0], bfr, acc[0][ct], 0, 0, 0);
        acc[1][ct] = __builtin_amdgcn_mfma_f32_16x16x32_bf16(af[1], bfr, acc[1][ct], 0, 0, 0);
      }
    }
  }
  #pragma unroll
  for (int pi = 0; pi < 2; ++pi)
    #pragma unroll
    for (int ct = 0; ct < 8; ++ct) {
      int col = ct * 16 + l15;
      #pragma unroll
      for (int r = 0; r < 4; ++r) {
        int row = (wv * 2 + pi) * 16 + quad * 4 + r;
        GT[(size_t)row * 1024 + j0 + col] = f2bf(acc[pi][ct][r]);
      }
    }
}

// ---------------- attn5: sim -> masked exp -> ph = (W@GT^T)/rsum + biasG ----------------
__global__ __launch_bounds__(256) void attn5_k(
    const ushort_t* __restrict__ gn_bf, const ushort_t* __restrict__ GT,
    const float* __restrict__ biasG, float* __restrict__ ph) {
  __shared__ ushort_t W[16 * SW];
  __shared__ float rsum[16];
  __shared__ int flags[63];
  int tid = threadIdx.x;
  int i0 = blockIdx.x * 16;
  int lane = tid & 63, wv = tid >> 6;
  int l15 = lane & 15, quad = lane >> 4;
  if (tid < 63) flags[tid] = 0;
  if (tid >= 64 && tid < 80) rsum[tid - 64] = 0.f;
  W[(tid >> 4) * SW + 1008 + (tid & 15)] = 0;   // zero k-pad cols 1008..1023
  __syncthreads();

  // phase 1: sim rows i0..i0+15 vs all j; exp; W strip -> LDS; rowsums; hot flags
  const ushort_t* abase = gn_bf + (size_t)(i0 + l15) * 128 + quad * 8;
  bf16x8 af0 = *reinterpret_cast<const bf16x8*>(abase);
  bf16x8 af1 = *reinterpret_cast<const bf16x8*>(abase + 32);
  bf16x8 af2 = *reinterpret_cast<const bf16x8*>(abase + 64);
  bf16x8 af3 = *reinterpret_cast<const bf16x8*>(abase + 96);
  float rs[4] = {0.f, 0.f, 0.f, 0.f};
  for (int jt = wv; jt < 63; jt += 4) {
    const ushort_t* bbase = gn_bf + (size_t)(jt * 16 + l15) * 128 + quad * 8;
    f32x4 d = {0.f, 0.f, 0.f, 0.f};
    d = __builtin_amdgcn_mfma_f32_16x16x32_bf16(af0, *reinterpret_cast<const bf16x8*>(bbase),      d, 0, 0, 0);
    d = __builtin_amdgcn_mfma_f32_16x16x32_bf16(af1, *reinterpret_cast<const bf16x8*>(bbase + 32), d, 0, 0, 0);
    d = __builtin_amdgcn_mfma_f32_16x16x32_bf16(af2, *reinterpret_cast<const bf16x8*>(bbase + 64), d, 0, 0, 0);
    d = __builtin_amdgcn_mfma_f32_16x16x32_bf16(af3, *reinterpret_cast<const bf16x8*>(bbase + 96), d, 0, 0, 0);
    int hot = 0;
    #pragma unroll
    for (int r = 0; r < 4; ++r) {
      float w = 0.f;
      if (d[r] > THRESH) { w = __expf(T_SOFT * (d[r] - 1.0f)); hot = 1; }
      ushort_t wb = f2bf(w);
      W[(quad * 4 + r) * SW + jt * 16 + l15] = wb;
      rs[r] += bf2f(wb);
    }
    if (hot) flags[jt] = 1;
  }
  #pragma unroll
  for (int r = 0; r < 4; ++r) {
    float v = rs[r];
    v += __shfl_xor(v, 1, 64); v += __shfl_xor(v, 2, 64);
    v += __shfl_xor(v, 4, 64); v += __shfl_xor(v, 8, 64);
    if (l15 == 0) atomicAdd(&rsum[quad * 4 + r], v);
  }
  __syncthreads();

  // phase 2: ph_strip = W @ GT^T (skip cold 32-j chunks); wave wv owns h-tiles wv*2, wv*2+1
  f32x4 acc2[2];
  acc2[0] = f32x4{0.f, 0.f, 0.f, 0.f};
  acc2[1] = f32x4{0.f, 0.f, 0.f, 0.f};
  for (int s = 0; s < 32; ++s) {
    int f = flags[2 * s] | ((2 * s + 1 < 63) ? flags[2 * s + 1] : 0);
    if (!f) continue;
    bf16x8 a = *reinterpret_cast<bf16x8*>(W + l15 * SW + s * 32 + quad * 8);
    #pragma unroll
    for (int t = 0; t < 2; ++t) {
      int h = (wv * 2 + t) * 16 + l15;
      bf16x8 bfr = *reinterpret_cast<const bf16x8*>(GT + (size_t)h * 1024 + s * 32 + quad * 8);
      acc2[t] = __builtin_amdgcn_mfma_f32_16x16x32_bf16(a, bfr, acc2[t], 0, 0, 0);
    }
  }
  #pragma unroll
  for (int t = 0; t < 2; ++t) {
    int h = (wv * 2 + t) * 16 + l15;
    float bg = biasG[h];
    #pragma unroll
    for (int r = 0; r < 4; ++r) {
      int row = quad * 4 + r;
      int gi = i0 + row;
      float inv = 1.f / fmaxf(rsum[row], 1e-30f);
      if (gi < 1000) ph[(size_t)gi * 128 + h] = acc2[t][r] * inv + bg;
    }
  }
}

// ---------------- final: out[b,c] = fc_b + sum_h relu(img_h[b,h]+ph[c,h]) * fc_w[h] ----------------
// 512 threads (8 waves -> 2 waves/SIMD); each thread 4 b-rows x 4 c-cols
__global__ __launch_bounds__(512) void final_k(
    const float* __restrict__ img_h, const float* __restrict__ ph,
    const float* __restrict__ fc_w, const float* __restrict__ fc_b,
    float* __restrict__ out) {
  __shared__ float ih[128][132];
  __shared__ float ps[64][132];
  __shared__ float ws_[128];
  int tid = threadIdx.x;
  int b0 = blockIdx.x * 128;
  int c0 = blockIdx.y * 64;
  for (int idx = tid; idx < 4096; idx += 512) {
    int row = idx >> 5, c4 = (idx & 31) * 4;
    float4 v = *reinterpret_cast<const float4*>(img_h + (size_t)(b0 + row) * 128 + c4);
    *reinterpret_cast<float4*>(&ih[row][c4]) = v;
  }
  for (int idx = tid; idx < 2048; idx += 512) {
    int row = idx >> 5, c4 = (idx & 31) * 4;
    int c = c0 + row;
    float4 v = make_float4(0.f, 0.f, 0.f, 0.f);
    if (c < 1000) v = *reinterpret_cast<const float4*>(ph + (size_t)c * 128 + c4);
    *reinterpret_cast<float4*>(&ps[row][c4]) = v;
  }
  if (tid < 128) ws_[tid] = fc_w[tid];
  __syncthreads();
  int tx = tid & 15, ty = tid >> 4;   // ty 0..31
  f32x2 acc[4][4] = {};
  const f32x2 zero2 = {0.f, 0.f};
  for (int h = 0; h < 128; h += 4) {
    float4 w4 = *reinterpret_cast<float4*>(&ws_[h]);
    f32x2 wlo = {w4.x, w4.y}, whi = {w4.z, w4.w};
    float4 a4[4], p4[4];
    #pragma unroll
    for (int i = 0; i < 4; ++i) a4[i] = *reinterpret_cast<float4*>(&ih[ty * 4 + i][h]);
    #pragma unroll
    for (int j = 0; j < 4; ++j) p4[j] = *reinterpret_cast<float4*>(&ps[tx * 4 + j][h]);
    #pragma unroll
    for (int i = 0; i < 4; ++i) {
      f32x2 alo = {a4[i].x, a4[i].y}, ahi = {a4[i].z, a4[i].w};
      #pragma unroll
      for (int j = 0; j < 4; ++j) {
        f32x2 plo = {p4[j].x, p4[j].y}, phi = {p4[j].z, p4[j].w};
        f32x2 t0 = __builtin_elementwise_max(alo + plo, zero2);
        f32x2 t1 = __builtin_elementwise_max(ahi + phi, zero2);
        acc[i][j] = acc[i][j] + t0 * wlo;
        acc[i][j] = acc[i][j] + t1 * whi;
      }
    }
  }
  float fb = fc_b[0];
  #pragma unroll
  for (int i = 0; i < 4; ++i) {
    int b = b0 + ty * 4 + i;
    int c = c0 + tx * 4;
    if (c < 1000) {
      float4 v = make_float4(acc[i][0].x + acc[i][0].y + fb, acc[i][1].x + acc[i][1].y + fb,
                             acc[i][2].x + acc[i][2].y + fb, acc[i][3].x + acc[i][3].y + fb);
      *reinterpret_cast<float4*>(out + (size_t)b * 1000 + c) = v;
    }
  }
}

extern "C" void kernel_launch(void* const* d_in, const int* in_sizes, int n_in,
                              void* d_out, int out_size, void* d_ws, size_t ws_size,
                              hipStream_t stream) {
  const float* image_feats = (const float*)d_in[0];   // [2048,2048]
  const float* img_proto   = (const float*)d_in[1];   // [1000,2048]
  const float* attributes  = (const float*)d_in[2];   // [1000,312]
  const float* att_g   = (const float*)d_in[4];       // [312,128]
  const float* slim_w  = (const float*)d_in[5];       // [2048,312]
  const float* slim_b  = (const float*)d_in[6];       // [312]
  const float* img_w   = (const float*)d_in[7];       // [2048,128]
  const float* proto_w = (const float*)d_in[8];       // [624,128]
  const float* proto_b = (const float*)d_in[9];       // [1,128]
  const float* fc_w    = (const float*)d_in[10];      // [128,1]
  const float* fc_b    = (const float*)d_in[11];      // [1]
  float* out = (float*)d_out;                         // [2048,1000]

  char* ws = (char*)d_ws;
  size_t o = 0;
  auto alloc = [&](size_t bytes) { size_t r = o; o += (bytes + 255) & ~(size_t)255; return r; };
  ushort_t* imgwT   = (ushort_t*)(ws + alloc(128ull * 2048 * 2));   // img_w^T bf16
  ushort_t* slimT   = (ushort_t*)(ws + alloc(320ull * 2048 * 2));   // slim_w^T bf16, rows 312..319 ZERO
  ushort_t* protowT = (ushort_t*)(ws + alloc(128ull * 640 * 2));    // proto_w^T bf16, K-pad zeros
  ushort_t* gn_bf   = (ushort_t*)(ws + alloc(1008ull * 128 * 2));   // normalized g bf16, tail zero
  ushort_t* poutN   = (ushort_t*)(ws + alloc(1024ull * 640 * 2));   // [attr | proto_red | 0] class-major bf16
  ushort_t* GT      = (ushort_t*)(ws + alloc(128ull * 1024 * 2));   // protowT @ poutN^T, bf16
  float* biasG     = (float*)(ws + alloc(128ull * 4));              // slim_b@proto_w + proto_b
  float* img_h     = (float*)(ws + alloc(2048ull * 128 * 4));       // | contiguous zero span
  float* pacc2     = (float*)(ws + alloc(1024ull * 320 * 4));       // | (tr3 zeroes both)
  float* ph        = (float*)(ws + alloc(1000ull * 128 * 4));

  // transposes (976) + poutN left copy (312) + zero img_h/pacc2 (144) + gn tail (1)
  tr3_k<<<1433, 256, 0, stream>>>(slim_w, slimT, img_w, imgwT, proto_w, protowT,
                                  attributes, poutN, gn_bf, img_h);

  // gn (125) + img_h splitK8 (128) + proto splitK8 -> pacc2 (192)
  mega_k<<<445, 256, 0, stream>>>(attributes, att_g, gn_bf,
                                  img_proto, slimT,
                                  image_feats, imgwT, img_h, pacc2);

  // pacc2 -> poutN cols 312..639
  conv_k<<<328, 256, 0, stream>>>(pacc2, poutN);

  // GT = protowT @ poutN^T (8) + biasG (1)
  g_k<<<9, 256, 0, stream>>>(protowT, poutN, proto_w, slim_b, proto_b, GT, biasG);

  // sim -> masked exp -> ph = (W@GT^T)/rsum + biasG
  attn5_k<<<63, 256, 0, stream>>>(gn_bf, GT, biasG, ph);

  final_k<<<dim3(16, 16), 512, 0, stream>>>(img_h, ph, fc_w, fc_b, out);
}

// Round 3
// 169.883 us; speedup vs baseline: 1.0556x; 1.0556x over previous
//
#include <hip/hip_runtime.h>

typedef unsigned short ushort_t;
typedef __bf16 bf16x8 __attribute__((ext_vector_type(8)));
typedef float f32x4 __attribute__((ext_vector_type(4)));
typedef float f32x2 __attribute__((ext_vector_type(2)));
typedef ushort_t us4 __attribute__((ext_vector_type(4)));

#define T_SOFT 32.0f
#define THRESH 0.76604444311897803f   // cos(40 deg)
#define SW 1048                       // W strip LDS row stride (bf16)

__device__ __forceinline__ ushort_t f2bf(float f) {
  union { float f; unsigned u; } x; x.f = f;
  unsigned r = (x.u + 0x7fffu + ((x.u >> 16) & 1u)) >> 16;  // RNE
  return (ushort_t)r;
}
__device__ __forceinline__ float bf2f(ushort_t h) {
  union { unsigned u; float f; } x; x.u = ((unsigned)h) << 16; return x.f;
}

// pack 4 fp32 -> 4 bf16
__device__ __forceinline__ us4 pack4(float4 x) {
  union { unsigned u[2]; us4 h; } r;
  union { float4 f; unsigned u[4]; } a;
  a.f = x;
  r.u[0] = __builtin_amdgcn_perm(a.u[1] + 0x8000u, a.u[0] + 0x8000u, 0x07060302u);
  r.u[1] = __builtin_amdgcn_perm(a.u[3] + 0x8000u, a.u[2] + 0x8000u, 0x07060302u);
  return r.h;
}

// ---------------- tr3: transposes + casts + biasG + tails ----------------
// grid 578: [0,256) imgwT tr, [256,336) protowT tr, [336,496) slim cast,
//           [496,576) attr cast, 576 gn tail, 577 biasG
__global__ __launch_bounds__(256) void tr3_k(const float* __restrict__ img_w, ushort_t* __restrict__ imgwT,
                                             const float* __restrict__ proto_w, ushort_t* __restrict__ protowT,
                                             const float* __restrict__ slim_w, ushort_t* __restrict__ slim_bf,
                                             const float* __restrict__ attributes, ushort_t* __restrict__ attr_bf,
                                             ushort_t* __restrict__ gn_bf,
                                             const float* __restrict__ slim_b, const float* __restrict__ proto_b,
                                             float* __restrict__ biasG) {
  int b = blockIdx.x, tid = threadIdx.x;
  if (b >= 336) {
    if (b < 496) {            // slim_bf[2048][320] = bf16(slim_w), cols 312..319 zero
      int t = (b - 336) * 256 + tid;       // 0..40959
      int row = t / 20, c0 = (t - row * 20) * 16;
      #pragma unroll
      for (int g = 0; g < 4; ++g) {
        int c4 = c0 + g * 4;
        us4 v = {0, 0, 0, 0};
        if (c4 < 312) v = pack4(*reinterpret_cast<const float4*>(slim_w + (size_t)row * 312 + c4));
        *reinterpret_cast<us4*>(slim_bf + (size_t)row * 320 + c4) = v;
      }
    } else if (b < 576) {     // attr_bf[1024][320] = bf16(attributes), pads zero
      int t = (b - 496) * 256 + tid;       // 0..20479
      int row = t / 20, c0 = (t - row * 20) * 16;
      #pragma unroll
      for (int g = 0; g < 4; ++g) {
        int c4 = c0 + g * 4;
        us4 v = {0, 0, 0, 0};
        if (row < 1000 && c4 < 312) v = pack4(*reinterpret_cast<const float4*>(attributes + (size_t)row * 312 + c4));
        *reinterpret_cast<us4*>(attr_bf + (size_t)row * 320 + c4) = v;
      }
    } else if (b == 576) {    // zero gn_bf rows 1000..1007
      us4 z = {0, 0, 0, 0};
      *reinterpret_cast<us4*>(gn_bf + 1000 * 128 + tid * 4) = z;
    } else {                  // biasG[h] = proto_b[h] + sum_n slim_b[n]*proto_w[312+n][h]
      int h = tid & 127;
      float acc = proto_b[h];
      for (int n = 0; n < 312; n += 4) {
        acc += slim_b[n + 0] * proto_w[(size_t)(312 + n) * 128 + h];
        acc += slim_b[n + 1] * proto_w[(size_t)(313 + n) * 128 + h];
        acc += slim_b[n + 2] * proto_w[(size_t)(314 + n) * 128 + h];
        acc += slim_b[n + 3] * proto_w[(size_t)(315 + n) * 128 + h];
      }
      if (tid < 128) biasG[h] = acc;
    }
    return;
  }
  __shared__ float tl[32][33];
  const float* src; ushort_t* dst; int R, C, Rpad, local;
  if (b < 256) { src = img_w;   dst = imgwT;   R = 2048; C = 128; Rpad = 2048; local = b;       }
  else         { src = proto_w; dst = protowT; R = 624;  C = 128; Rpad = 640;  local = b - 256; }
  int rt = local >> 2, ct = local & 3;
  int r0 = rt * 32, c0 = ct * 32;
  #pragma unroll
  for (int p = 0; p < 4; ++p) {
    int idx = p * 256 + tid;
    int rr = idx >> 5, cc = idx & 31;
    float v = 0.f;
    if (r0 + rr < R && c0 + cc < C) v = src[(size_t)(r0 + rr) * C + (c0 + cc)];
    tl[cc][rr] = v;
  }
  __syncthreads();
  int cc = tid >> 3, rq = tid & 7;
  us4 o;
  o[0] = f2bf(tl[cc][rq * 4 + 0]);
  o[1] = f2bf(tl[cc][rq * 4 + 1]);
  o[2] = f2bf(tl[cc][rq * 4 + 2]);
  o[3] = f2bf(tl[cc][rq * 4 + 3]);
  *reinterpret_cast<us4*>(dst + (size_t)(c0 + cc) * Rpad + r0 + rq * 4) = o;
}

// ---------------- img_h GEMM: split-K chunk -> PLAIN-STORE partial buffer ----------------
__device__ __forceinline__ void gemm_imgh(const float* __restrict__ A, const ushort_t* __restrict__ BT,
                                          float* __restrict__ Cp, int r0, int k0,
                                          ushort_t* __restrict__ As, ushort_t* __restrict__ Bs, int tid) {
  const int SA = 72;
  int lane = tid & 63, wv = tid >> 6;
  int l15 = lane & 15, quad = lane >> 4;
  int arow = tid >> 4, akq = tid & 15;
  int brow = tid >> 3, bkq = tid & 7;
  const float* agp[8];
  #pragma unroll
  for (int p = 0; p < 8; ++p) agp[p] = A + (size_t)(r0 + arow + p * 16) * 2048 + k0 + akq * 4;
  const ushort_t* bgp[4];
  #pragma unroll
  for (int p = 0; p < 4; ++p) bgp[p] = BT + (size_t)(brow + p * 32) * 2048 + k0 + bkq * 8;

  float4 ap[8]; bf16x8 bp[4];
  #pragma unroll
  for (int p = 0; p < 8; ++p) ap[p] = *reinterpret_cast<const float4*>(agp[p]);
  #pragma unroll
  for (int p = 0; p < 4; ++p) bp[p] = *reinterpret_cast<const bf16x8*>(bgp[p]);

  f32x4 acc[2][8];
  #pragma unroll
  for (int i = 0; i < 2; ++i)
    #pragma unroll
    for (int j = 0; j < 8; ++j) acc[i][j] = f32x4{0.f, 0.f, 0.f, 0.f};

  for (int s = 0; s < 4; ++s) {
    if (s) __syncthreads();
    #pragma unroll
    for (int p = 0; p < 8; ++p)
      *reinterpret_cast<us4*>(As + (arow + p * 16) * SA + akq * 4) = pack4(ap[p]);
    #pragma unroll
    for (int p = 0; p < 4; ++p)
      *reinterpret_cast<bf16x8*>(Bs + (brow + p * 32) * SA + bkq * 8) = bp[p];
    if (s + 1 < 4) {
      #pragma unroll
      for (int p = 0; p < 8; ++p) ap[p] = *reinterpret_cast<const float4*>(agp[p] + 64);
      #pragma unroll
      for (int p = 0; p < 4; ++p) bp[p] = *reinterpret_cast<const bf16x8*>(bgp[p] + 64);
      #pragma unroll
      for (int p = 0; p < 8; ++p) agp[p] += 64;
      #pragma unroll
      for (int p = 0; p < 4; ++p) bgp[p] += 64;
    }
    __syncthreads();
    #pragma unroll
    for (int kh = 0; kh < 2; ++kh) {
      bf16x8 af[2];
      #pragma unroll
      for (int pi = 0; pi < 2; ++pi)
        af[pi] = *reinterpret_cast<bf16x8*>(As + ((wv * 2 + pi) * 16 + l15) * SA + kh * 32 + quad * 8);
      #pragma unroll
      for (int ct = 0; ct < 8; ++ct) {
        bf16x8 bfr = *reinterpret_cast<bf16x8*>(Bs + (ct * 16 + l15) * SA + kh * 32 + quad * 8);
        acc[0][ct] = __builtin_amdgcn_mfma_f32_16x16x32_bf16(af[0], bfr, acc[0][ct], 0, 0, 0);
        acc[1][ct] = __builtin_amdgcn_mfma_f32_16x16x32_bf16(af[1], bfr, acc[1][ct], 0, 0, 0);
      }
    }
  }
  #pragma unroll
  for (int pi = 0; pi < 2; ++pi)
    #pragma unroll
    for (int ct = 0; ct < 8; ++ct) {
      int col = ct * 16 + l15;
      #pragma unroll
      for (int r = 0; r < 4; ++r) {
        int row = r0 + (wv * 2 + pi) * 16 + quad * 4 + r;
        Cp[(size_t)row * 128 + col] = acc[pi][ct][r];
      }
    }
}

// ---------------- generic bf16 x bf16 GEMM core: C[128][128] = A[128,K] @ B[128,K]^T ----------------
__device__ __forceinline__ void gemm_bb(const ushort_t* __restrict__ A, int sa,
                                        const ushort_t* __restrict__ B, int sb,
                                        int nsteps, ushort_t* __restrict__ As, ushort_t* __restrict__ Bs,
                                        int tid, f32x4 acc[2][8]) {
  const int SA = 72;
  int lane = tid & 63, wv = tid >> 6;
  int l15 = lane & 15, quad = lane >> 4;
  int hrow = tid >> 3, hkq = tid & 7;
  const ushort_t* ap = A + (size_t)hrow * sa + hkq * 8;
  const ushort_t* bp = B + (size_t)hrow * sb + hkq * 8;
  bf16x8 ar[4], br[4];
  #pragma unroll
  for (int p = 0; p < 4; ++p) {
    ar[p] = *reinterpret_cast<const bf16x8*>(ap + (size_t)p * 32 * sa);
    br[p] = *reinterpret_cast<const bf16x8*>(bp + (size_t)p * 32 * sb);
  }
  for (int s = 0; s < nsteps; ++s) {
    if (s) __syncthreads();
    #pragma unroll
    for (int p = 0; p < 4; ++p) {
      *reinterpret_cast<bf16x8*>(As + (hrow + p * 32) * SA + hkq * 8) = ar[p];
      *reinterpret_cast<bf16x8*>(Bs + (hrow + p * 32) * SA + hkq * 8) = br[p];
    }
    if (s + 1 < nsteps) {
      ap += 64; bp += 64;
      #pragma unroll
      for (int p = 0; p < 4; ++p) {
        ar[p] = *reinterpret_cast<const bf16x8*>(ap + (size_t)p * 32 * sa);
        br[p] = *reinterpret_cast<const bf16x8*>(bp + (size_t)p * 32 * sb);
      }
    }
    __syncthreads();
    #pragma unroll
    for (int kh = 0; kh < 2; ++kh) {
      bf16x8 af[2];
      #pragma unroll
      for (int pi = 0; pi < 2; ++pi)
        af[pi] = *reinterpret_cast<bf16x8*>(As + ((wv * 2 + pi) * 16 + l15) * SA + kh * 32 + quad * 8);
      #pragma unroll
      for (int ct = 0; ct < 8; ++ct) {
        bf16x8 bfr = *reinterpret_cast<bf16x8*>(Bs + (ct * 16 + l15) * SA + kh * 32 + quad * 8);
        acc[0][ct] = __builtin_amdgcn_mfma_f32_16x16x32_bf16(af[0], bfr, acc[0][ct], 0, 0, 0);
        acc[1][ct] = __builtin_amdgcn_mfma_f32_16x16x32_bf16(af[1], bfr, acc[1][ct], 0, 0, 0);
      }
    }
  }
}

// ---------------- bf16(A) x fp32(B) GEMM core, B rows clamped ----------------
__device__ __forceinline__ void gemm_b32(const ushort_t* __restrict__ A, int sa,
                                         const float* __restrict__ Bsrc, int sb, int brow0, int browmax,
                                         int nsteps, ushort_t* __restrict__ As, ushort_t* __restrict__ Bs,
                                         int tid, f32x4 acc[2][8]) {
  const int SA = 72;
  int lane = tid & 63, wv = tid >> 6;
  int l15 = lane & 15, quad = lane >> 4;
  int hrow = tid >> 3, hkq = tid & 7;
  int frow = tid >> 4, fkq = tid & 15;
  const ushort_t* ap = A + (size_t)hrow * sa + hkq * 8;
  const float* bgp[8];
  #pragma unroll
  for (int p = 0; p < 8; ++p) {
    int r = brow0 + frow + p * 16; if (r > browmax) r = browmax;
    bgp[p] = Bsrc + (size_t)r * sb + fkq * 4;
  }
  bf16x8 ar[4]; float4 brf[8];
  #pragma unroll
  for (int p = 0; p < 4; ++p) ar[p] = *reinterpret_cast<const bf16x8*>(ap + (size_t)p * 32 * sa);
  #pragma unroll
  for (int p = 0; p < 8; ++p) brf[p] = *reinterpret_cast<const float4*>(bgp[p]);
  for (int s = 0; s < nsteps; ++s) {
    if (s) __syncthreads();
    #pragma unroll
    for (int p = 0; p < 4; ++p)
      *reinterpret_cast<bf16x8*>(As + (hrow + p * 32) * SA + hkq * 8) = ar[p];
    #pragma unroll
    for (int p = 0; p < 8; ++p)
      *reinterpret_cast<us4*>(Bs + (frow + p * 16) * SA + fkq * 4) = pack4(brf[p]);
    if (s + 1 < nsteps) {
      ap += 64;
      #pragma unroll
      for (int p = 0; p < 4; ++p) ar[p] = *reinterpret_cast<const bf16x8*>(ap + (size_t)p * 32 * sa);
      #pragma unroll
      for (int p = 0; p < 8; ++p) { bgp[p] += 64; brf[p] = *reinterpret_cast<const float4*>(bgp[p]); }
    }
    __syncthreads();
    #pragma unroll
    for (int kh = 0; kh < 2; ++kh) {
      bf16x8 af[2];
      #pragma unroll
      for (int pi = 0; pi < 2; ++pi)
        af[pi] = *reinterpret_cast<bf16x8*>(As + ((wv * 2 + pi) * 16 + l15) * SA + kh * 32 + quad * 8);
      #pragma unroll
      for (int ct = 0; ct < 8; ++ct) {
        bf16x8 bfr = *reinterpret_cast<bf16x8*>(Bs + (ct * 16 + l15) * SA + kh * 32 + quad * 8);
        acc[0][ct] = __builtin_amdgcn_mfma_f32_16x16x32_bf16(af[0], bfr, acc[0][ct], 0, 0, 0);
        acc[1][ct] = __builtin_amdgcn_mfma_f32_16x16x32_bf16(af[1], bfr, acc[1][ct], 0, 0, 0);
      }
    }
  }
}

// ---------------- mega: gn (125) + img_h splitK8 partials (128) + M2T (16) ----------------
__global__ __launch_bounds__(256) void mega_k(
    const float* __restrict__ attributes, const float* __restrict__ att_g,
    ushort_t* __restrict__ gn_bf,
    const float* __restrict__ image_feats, const ushort_t* __restrict__ imgwT,
    float* __restrict__ ihp,
    const ushort_t* __restrict__ protowT, const ushort_t* __restrict__ slim_bf,
    ushort_t* __restrict__ M2T) {
  __shared__ ushort_t As[128 * 72];
  __shared__ ushort_t Bs[128 * 72];
  int b = blockIdx.x, tid = threadIdx.x;
  if (b < 125) {
    __shared__ float a_lds[8][316];
    __shared__ float red2[8][2];
    int h = tid & 127;
    int c0 = b * 8;
    for (int idx = tid; idx < 8 * 312; idx += 256) {
      int r = idx / 312;
      int k = idx - r * 312;
      a_lds[r][k] = attributes[(c0 + r) * 312 + k];
    }
    __syncthreads();
    float acc[8] = {0.f,0.f,0.f,0.f,0.f,0.f,0.f,0.f};
    #pragma unroll 2
    for (int k = 0; k < 312; k += 4) {
      float w0 = att_g[(k + 0) * 128 + h];
      float w1 = att_g[(k + 1) * 128 + h];
      float w2 = att_g[(k + 2) * 128 + h];
      float w3 = att_g[(k + 3) * 128 + h];
      #pragma unroll
      for (int r = 0; r < 8; ++r) {
        float4 a4 = *reinterpret_cast<const float4*>(&a_lds[r][k]);
        acc[r] += a4.x * w0 + a4.y * w1 + a4.z * w2 + a4.w * w3;
      }
    }
    int lane = tid & 63, wvid = (tid >> 6) & 1;
    #pragma unroll
    for (int r = 0; r < 8; ++r) {
      float v = acc[r] * acc[r];
      #pragma unroll
      for (int off = 32; off > 0; off >>= 1) v += __shfl_xor(v, off, 64);
      if (lane == 0) red2[r][wvid] = v;
    }
    __syncthreads();
    #pragma unroll
    for (int r = 0; r < 8; ++r) {
      float nrm = fmaxf(sqrtf(red2[r][0] + red2[r][1]), 1e-12f);
      gn_bf[(c0 + r) * 128 + h] = f2bf(acc[r] / nrm);
    }
    return;
  }
  b -= 125;
  if (b < 128) {
    int tile = b >> 3, kc = b & 7;
    gemm_imgh(image_feats, imgwT, ihp + (size_t)kc * 2048 * 128, tile * 128, kc * 256, As, Bs, tid);
    return;
  }
  // M2T GEMM: M2T[h][d] = sum_n proto_w2T[h][n] * slim_w[d][n]; K=320 (5 steps), no split
  b -= 128;                    // 0..15 -> d-tile
  int c0 = b * 128;
  f32x4 acc[2][8];
  #pragma unroll
  for (int i = 0; i < 2; ++i)
    #pragma unroll
    for (int j = 0; j < 8; ++j) acc[i][j] = f32x4{0.f, 0.f, 0.f, 0.f};
  gemm_bb(protowT + 312, 640, slim_bf + (size_t)c0 * 320, 320, 5, As, Bs, tid, acc);
  int lane = tid & 63, wv = tid >> 6;
  int l15 = lane & 15, quad = lane >> 4;
  #pragma unroll
  for (int pi = 0; pi < 2; ++pi)
    #pragma unroll
    for (int ct = 0; ct < 8; ++ct) {
      int col = c0 + ct * 16 + l15;
      #pragma unroll
      for (int r = 0; r < 4; ++r) {
        int row = (wv * 2 + pi) * 16 + quad * 4 + r;
        M2T[(size_t)row * 2048 + col] = f2bf(acc[pi][ct][r]);
      }
    }
}

// ---------------- k3: img_h reduce (64) + GT-GEMM partials (40) ----------------
__global__ __launch_bounds__(256) void k3_k(
    const float* __restrict__ ihp, float* __restrict__ img_h,
    const ushort_t* __restrict__ protowT, const ushort_t* __restrict__ M2T,
    const ushort_t* __restrict__ attr_bf, const float* __restrict__ img_proto,
    float* __restrict__ GT_part) {
  __shared__ ushort_t As[128 * 72];
  __shared__ ushort_t Bs[128 * 72];
  int b = blockIdx.x, tid = threadIdx.x;
  if (b < 64) {                // img_h[r][h] = sum_{c<8} ihp[c][r][h]
    int t = b * 256 + tid;     // 0..16383
    size_t base = (size_t)t * 16;
    #pragma unroll
    for (int g = 0; g < 4; ++g) {
      float4 s = *reinterpret_cast<const float4*>(ihp + base + g * 4);
      #pragma unroll
      for (int c = 1; c < 8; ++c) {
        float4 v = *reinterpret_cast<const float4*>(ihp + (size_t)c * 262144 + base + g * 4);
        s.x += v.x; s.y += v.y; s.z += v.z; s.w += v.w;
      }
      *reinterpret_cast<float4*>(img_h + base + g * 4) = s;
    }
    return;
  }
  int q = b - 64;              // 0..39
  int jt = q / 5, ch = q - jt * 5;
  int j0 = jt * 128;
  f32x4 acc[2][8];
  #pragma unroll
  for (int i = 0; i < 2; ++i)
    #pragma unroll
    for (int j = 0; j < 8; ++j) acc[i][j] = f32x4{0.f, 0.f, 0.f, 0.f};
  if (ch == 0) {
    // GT0[h][j] = sum_{n<320} protowT[h][n] * attr_bf[j][n]  (attr pad cols are zero)
    gemm_bb(protowT, 640, attr_bf + (size_t)j0 * 320, 320, 5, As, Bs, tid, acc);
  } else {
    int k0 = (ch - 1) * 512;
    // GTc[h][j] = sum_{d in chunk} M2T[h][d] * img_proto[j][d]  (j>=1000 clamped; W=0 there)
    gemm_b32(M2T + k0, 2048, img_proto + k0, 2048, j0, 999, 8, As, Bs, tid, acc);
  }
  int lane = tid & 63, wv = tid >> 6;
  int l15 = lane & 15, quad = lane >> 4;
  float* dst = GT_part + (size_t)ch * 128 * 1024;
  #pragma unroll
  for (int pi = 0; pi < 2; ++pi)
    #pragma unroll
    for (int ct = 0; ct < 8; ++ct) {
      int col = j0 + ct * 16 + l15;
      #pragma unroll
      for (int r = 0; r < 4; ++r) {
        int row = (wv * 2 + pi) * 16 + quad * 4 + r;
        dst[(size_t)row * 1024 + col] = acc[pi][ct][r];
      }
    }
}

// ---------------- k4: GT = bf16( sum_{c<5} GT_part[c] + biasG[h] ) ----------------
__global__ __launch_bounds__(256) void k4_k(const float* __restrict__ GT_part,
                                            const float* __restrict__ biasG,
                                            ushort_t* __restrict__ GT) {
  int t = blockIdx.x * 256 + threadIdx.x;   // 0..8191
  size_t base = (size_t)t * 16;
  int row = (int)(base >> 10);
  float bg = biasG[row];
  #pragma unroll
  for (int g = 0; g < 4; ++g) {
    float4 s = *reinterpret_cast<const float4*>(GT_part + base + g * 4);
    #pragma unroll
    for (int c = 1; c < 5; ++c) {
      float4 v = *reinterpret_cast<const float4*>(GT_part + (size_t)c * 131072 + base + g * 4);
      s.x += v.x; s.y += v.y; s.z += v.z; s.w += v.w;
    }
    s.x += bg; s.y += bg; s.z += bg; s.w += bg;
    *reinterpret_cast<us4*>(GT + base + g * 4) = pack4(s);
  }
}

// ---------------- attn5: sim -> masked exp -> ph = (W@GT^T)/rsum (bias folded in GT) ----------------
__global__ __launch_bounds__(256) void attn5_k(
    const ushort_t* __restrict__ gn_bf, const ushort_t* __restrict__ GT,
    float* __restrict__ ph) {
  __shared__ ushort_t W[16 * SW];
  __shared__ float rsum[16];
  __shared__ int flags[63];
  int tid = threadIdx.x;
  int i0 = blockIdx.x * 16;
  int lane = tid & 63, wv = tid >> 6;
  int l15 = lane & 15, quad = lane >> 4;
  if (tid < 63) flags[tid] = 0;
  if (tid >= 64 && tid < 80) rsum[tid - 64] = 0.f;
  W[(tid >> 4) * SW + 1008 + (tid & 15)] = 0;   // zero k-pad cols 1008..1023
  __syncthreads();

  const ushort_t* abase = gn_bf + (size_t)(i0 + l15) * 128 + quad * 8;
  bf16x8 af0 = *reinterpret_cast<const bf16x8*>(abase);
  bf16x8 af1 = *reinterpret_cast<const bf16x8*>(abase + 32);
  bf16x8 af2 = *reinterpret_cast<const bf16x8*>(abase + 64);
  bf16x8 af3 = *reinterpret_cast<const bf16x8*>(abase + 96);
  float rs[4] = {0.f, 0.f, 0.f, 0.f};
  for (int jt = wv; jt < 63; jt += 4) {
    const ushort_t* bbase = gn_bf + (size_t)(jt * 16 + l15) * 128 + quad * 8;
    f32x4 d = {0.f, 0.f, 0.f, 0.f};
    d = __builtin_amdgcn_mfma_f32_16x16x32_bf16(af0, *reinterpret_cast<const bf16x8*>(bbase),      d, 0, 0, 0);
    d = __builtin_amdgcn_mfma_f32_16x16x32_bf16(af1, *reinterpret_cast<const bf16x8*>(bbase + 32), d, 0, 0, 0);
    d = __builtin_amdgcn_mfma_f32_16x16x32_bf16(af2, *reinterpret_cast<const bf16x8*>(bbase + 64), d, 0, 0, 0);
    d = __builtin_amdgcn_mfma_f32_16x16x32_bf16(af3, *reinterpret_cast<const bf16x8*>(bbase + 96), d, 0, 0, 0);
    int hot = 0;
    #pragma unroll
    for (int r = 0; r < 4; ++r) {
      float w = 0.f;
      if (d[r] > THRESH) { w = __expf(T_SOFT * (d[r] - 1.0f)); hot = 1; }
      ushort_t wb = f2bf(w);
      W[(quad * 4 + r) * SW + jt * 16 + l15] = wb;
      rs[r] += bf2f(wb);
    }
    if (hot) flags[jt] = 1;
  }
  #pragma unroll
  for (int r = 0; r < 4; ++r) {
    float v = rs[r];
    v += __shfl_xor(v, 1, 64); v += __shfl_xor(v, 2, 64);
    v += __shfl_xor(v, 4, 64); v += __shfl_xor(v, 8, 64);
    if (l15 == 0) atomicAdd(&rsum[quad * 4 + r], v);
  }
  __syncthreads();

  f32x4 acc2[2];
  acc2[0] = f32x4{0.f, 0.f, 0.f, 0.f};
  acc2[1] = f32x4{0.f, 0.f, 0.f, 0.f};
  for (int s = 0; s < 32; ++s) {
    int f = flags[2 * s] | ((2 * s + 1 < 63) ? flags[2 * s + 1] : 0);
    if (!f) continue;
    bf16x8 a = *reinterpret_cast<bf16x8*>(W + l15 * SW + s * 32 + quad * 8);
    #pragma unroll
    for (int t = 0; t < 2; ++t) {
      int h = (wv * 2 + t) * 16 + l15;
      bf16x8 bfr = *reinterpret_cast<const bf16x8*>(GT + (size_t)h * 1024 + s * 32 + quad * 8);
      acc2[t] = __builtin_amdgcn_mfma_f32_16x16x32_bf16(a, bfr, acc2[t], 0, 0, 0);
    }
  }
  #pragma unroll
  for (int t = 0; t < 2; ++t) {
    int h = (wv * 2 + t) * 16 + l15;
    #pragma unroll
    for (int r = 0; r < 4; ++r) {
      int row = quad * 4 + r;
      int gi = i0 + row;
      float inv = 1.f / fmaxf(rsum[row], 1e-30f);
      if (gi < 1000) ph[(size_t)gi * 128 + h] = acc2[t][r] * inv;
    }
  }
}

// ---------------- final: out[b,c] = fc_b + sum_h relu(img_h[b,h]+ph[c,h]) * fc_w[h] ----------------
__global__ __launch_bounds__(512) void final_k(
    const float* __restrict__ img_h, const float* __restrict__ ph,
    const float* __restrict__ fc_w, const float* __restrict__ fc_b,
    float* __restrict__ out) {
  __shared__ float ih[128][132];
  __shared__ float ps[64][132];
  __shared__ float ws_[128];
  int tid = threadIdx.x;
  int b0 = blockIdx.x * 128;
  int c0 = blockIdx.y * 64;
  for (int idx = tid; idx < 4096; idx += 512) {
    int row = idx >> 5, c4 = (idx & 31) * 4;
    float4 v = *reinterpret_cast<const float4*>(img_h + (size_t)(b0 + row) * 128 + c4);
    *reinterpret_cast<float4*>(&ih[row][c4]) = v;
  }
  for (int idx = tid; idx < 2048; idx += 512) {
    int row = idx >> 5, c4 = (idx & 31) * 4;
    int c = c0 + row;
    float4 v = make_float4(0.f, 0.f, 0.f, 0.f);
    if (c < 1000) v = *reinterpret_cast<const float4*>(ph + (size_t)c * 128 + c4);
    *reinterpret_cast<float4*>(&ps[row][c4]) = v;
  }
  if (tid < 128) ws_[tid] = fc_w[tid];
  __syncthreads();
  int tx = tid & 15, ty = tid >> 4;   // ty 0..31
  f32x2 acc[4][4] = {};
  const f32x2 zero2 = {0.f, 0.f};
  for (int h = 0; h < 128; h += 4) {
    float4 w4 = *reinterpret_cast<float4*>(&ws_[h]);
    f32x2 wlo = {w4.x, w4.y}, whi = {w4.z, w4.w};
    float4 a4[4], p4[4];
    #pragma unroll
    for (int i = 0; i < 4; ++i) a4[i] = *reinterpret_cast<float4*>(&ih[ty * 4 + i][h]);
    #pragma unroll
    for (int j = 0; j < 4; ++j) p4[j] = *reinterpret_cast<float4*>(&ps[tx * 4 + j][h]);
    #pragma unroll
    for (int i = 0; i < 4; ++i) {
      f32x2 alo = {a4[i].x, a4[i].y}, ahi = {a4[i].z, a4[i].w};
      #pragma unroll
      for (int j = 0; j < 4; ++j) {
        f32x2 plo = {p4[j].x, p4[j].y}, phi = {p4[j].z, p4[j].w};
        f32x2 t0 = __builtin_elementwise_max(alo + plo, zero2);
        f32x2 t1 = __builtin_elementwise_max(ahi + phi, zero2);
        acc[i][j] = acc[i][j] + t0 * wlo;
        acc[i][j] = acc[i][j] + t1 * whi;
      }
    }
  }
  float fb = fc_b[0];
  #pragma unroll
  for (int i = 0; i < 4; ++i) {
    int b = b0 + ty * 4 + i;
    int c = c0 + tx * 4;
    if (c < 1000) {
      float4 v = make_float4(acc[i][0].x + acc[i][0].y + fb, acc[i][1].x + acc[i][1].y + fb,
                             acc[i][2].x + acc[i][2].y + fb, acc[i][3].x + acc[i][3].y + fb);
      *reinterpret_cast<float4*>(out + (size_t)b * 1000 + c) = v;
    }
  }
}

extern "C" void kernel_launch(void* const* d_in, const int* in_sizes, int n_in,
                              void* d_out, int out_size, void* d_ws, size_t ws_size,
                              hipStream_t stream) {
  const float* image_feats = (const float*)d_in[0];   // [2048,2048]
  const float* img_proto   = (const float*)d_in[1];   // [1000,2048]
  const float* attributes  = (const float*)d_in[2];   // [1000,312]
  const float* att_g   = (const float*)d_in[4];       // [312,128]
  const float* slim_w  = (const float*)d_in[5];       // [2048,312]
  const float* slim_b  = (const float*)d_in[6];       // [312]
  const float* img_w   = (const float*)d_in[7];       // [2048,128]
  const float* proto_w = (const float*)d_in[8];       // [624,128]
  const float* proto_b = (const float*)d_in[9];       // [1,128]
  const float* fc_w    = (const float*)d_in[10];      // [128,1]
  const float* fc_b    = (const float*)d_in[11];      // [1]
  float* out = (float*)d_out;                         // [2048,1000]

  char* ws = (char*)d_ws;
  size_t o = 0;
  auto alloc = [&](size_t bytes) { size_t r = o; o += (bytes + 255) & ~(size_t)255; return r; };
  ushort_t* imgwT   = (ushort_t*)(ws + alloc(128ull * 2048 * 2));   // img_w^T bf16
  ushort_t* protowT = (ushort_t*)(ws + alloc(128ull * 640 * 2));    // proto_w^T bf16, K-pad zeros
  ushort_t* slim_bf = (ushort_t*)(ws + alloc(2048ull * 320 * 2));   // slim_w bf16, K-pad zeros
  ushort_t* attr_bf = (ushort_t*)(ws + alloc(1024ull * 320 * 2));   // attributes bf16, pads zero
  ushort_t* gn_bf   = (ushort_t*)(ws + alloc(1008ull * 128 * 2));   // normalized g bf16, tail zero
  ushort_t* M2T     = (ushort_t*)(ws + alloc(128ull * 2048 * 2));   // (slim_w @ proto_w2)^T bf16
  ushort_t* GT      = (ushort_t*)(ws + alloc(128ull * 1024 * 2));   // Gn^T + biasG, bf16
  float* biasG     = (float*)(ws + alloc(128ull * 4));              // slim_b@proto_w2 + proto_b
  float* ihp       = (float*)(ws + alloc(8ull * 2048 * 128 * 4));   // img_h split-K partials
  float* GT_part   = (float*)(ws + alloc(5ull * 128 * 1024 * 4));   // GT split-K partials
  float* img_h     = (float*)(ws + alloc(2048ull * 128 * 4));
  float* ph        = (float*)(ws + alloc(1000ull * 128 * 4));

  // transposes + casts + biasG + tails (no buffer pre-zeroing needed anymore)
  tr3_k<<<578, 256, 0, stream>>>(img_w, imgwT, proto_w, protowT, slim_w, slim_bf,
                                 attributes, attr_bf, gn_bf, slim_b, proto_b, biasG);

  // gn (125) + img_h split-K partials (128) + M2T (16)
  mega_k<<<269, 256, 0, stream>>>(attributes, att_g, gn_bf,
                                  image_feats, imgwT, ihp, protowT, slim_bf, M2T);

  // img_h reduce (64) + GT-GEMM partials (40)
  k3_k<<<104, 256, 0, stream>>>(ihp, img_h, protowT, M2T, attr_bf, img_proto, GT_part);

  // GT reduce + bias fold
  k4_k<<<32, 256, 0, stream>>>(GT_part, biasG, GT);

  // sim -> masked exp -> ph
  attn5_k<<<63, 256, 0, stream>>>(gn_bf, GT, ph);

  final_k<<<dim3(16, 16), 512, 0, stream>>>(img_h, ph, fc_w, fc_b, out);
}

// Round 4
// 168.972 us; speedup vs baseline: 1.0613x; 1.0054x over previous
//
#include <hip/hip_runtime.h>

typedef unsigned short ushort_t;
typedef __bf16 bf16x8 __attribute__((ext_vector_type(8)));
typedef float f32x4 __attribute__((ext_vector_type(4)));
typedef float f32x2 __attribute__((ext_vector_type(2)));
typedef ushort_t us4 __attribute__((ext_vector_type(4)));

#define T_SOFT 32.0f
#define THRESH 0.76604444311897803f   // cos(40 deg)
#define SW 1048                       // W strip LDS row stride (bf16)
#define SA 72                         // GEMM LDS row stride (bf16)

__device__ __forceinline__ ushort_t f2bf(float f) {
  union { float f; unsigned u; } x; x.f = f;
  unsigned r = (x.u + 0x7fffu + ((x.u >> 16) & 1u)) >> 16;  // RNE
  return (ushort_t)r;
}
__device__ __forceinline__ float bf2f(ushort_t h) {
  union { unsigned u; float f; } x; x.u = ((unsigned)h) << 16; return x.f;
}

// pack 4 fp32 -> 4 bf16
__device__ __forceinline__ us4 pack4(float4 x) {
  union { unsigned u[2]; us4 h; } r;
  union { float4 f; unsigned u[4]; } a;
  a.f = x;
  r.u[0] = __builtin_amdgcn_perm(a.u[1] + 0x8000u, a.u[0] + 0x8000u, 0x07060302u);
  r.u[1] = __builtin_amdgcn_perm(a.u[3] + 0x8000u, a.u[2] + 0x8000u, 0x07060302u);
  return r.h;
}

// ---- transpose-stage: dst[ncol][krow] <- src[rbase+krow][nbase+ncol], krow<64, ncol<128 ----
// rows >= rlimit read as 0. bf16-cast on the fly. 256 threads.
__device__ __forceinline__ void stage_T(const float* __restrict__ src, int srs, int rbase, int rlimit,
                                        int nbase, ushort_t* __restrict__ dst, int tid) {
  int kg = (tid >> 4) * 4;        // src-row group base 0,4,..,60
  int ns = (tid & 15) * 8;        // col segment
  float v[4][8];
  #pragma unroll
  for (int i = 0; i < 4; ++i) {
    int r = rbase + kg + i;
    float4 a = make_float4(0.f,0.f,0.f,0.f), c = make_float4(0.f,0.f,0.f,0.f);
    if (r < rlimit) {
      a = *reinterpret_cast<const float4*>(src + (size_t)r * srs + nbase + ns);
      c = *reinterpret_cast<const float4*>(src + (size_t)r * srs + nbase + ns + 4);
    }
    v[i][0]=a.x; v[i][1]=a.y; v[i][2]=a.z; v[i][3]=a.w;
    v[i][4]=c.x; v[i][5]=c.y; v[i][6]=c.z; v[i][7]=c.w;
  }
  #pragma unroll
  for (int j = 0; j < 8; ++j) {
    us4 o;
    o[0] = f2bf(v[0][j]); o[1] = f2bf(v[1][j]); o[2] = f2bf(v[2][j]); o[3] = f2bf(v[3][j]);
    *reinterpret_cast<us4*>(dst + (size_t)(ns + j) * SA + kg) = o;
  }
}

// ---- row-stage: dst[row][k] <- src[rowbase+row (clamped)][kbase+k], k<64; cols >= climit -> 0 ----
__device__ __forceinline__ void stage_R(const float* __restrict__ src, int srs, int rowbase, int rowmax,
                                        int kbase, int climit, ushort_t* __restrict__ dst, int tid) {
  int frow = tid >> 4;            // 16 rows/pass x 8 passes
  int fk = (tid & 15) * 4;
  #pragma unroll
  for (int p = 0; p < 8; ++p) {
    int row = rowbase + frow + p * 16; if (row > rowmax) row = rowmax;
    int k = kbase + fk;
    float4 val = make_float4(0.f,0.f,0.f,0.f);
    if (k < climit) val = *reinterpret_cast<const float4*>(src + (size_t)row * srs + k);
    *reinterpret_cast<us4*>(dst + (size_t)(frow + p * 16) * SA + fk) = pack4(val);
  }
}

// ---- bf16 row-stage (no mask): dst[row][k] <- src[row][kbase+k] ----
__device__ __forceinline__ void stage_Abf(const ushort_t* __restrict__ src, int srs, int kbase,
                                          ushort_t* __restrict__ dst, int tid) {
  int hrow = tid >> 3;            // 32 rows/pass x 4 passes
  int hk = (tid & 7) * 8;
  #pragma unroll
  for (int p = 0; p < 4; ++p)
    *reinterpret_cast<bf16x8*>(dst + (size_t)(hrow + p * 32) * SA + hk) =
      *reinterpret_cast<const bf16x8*>(src + (size_t)(hrow + p * 32) * srs + kbase + hk);
}

// ---- one 128x128x64 MFMA step over staged As/Bs ----
__device__ __forceinline__ void mfma8(ushort_t* __restrict__ As, ushort_t* __restrict__ Bs,
                                      int tid, f32x4 acc[2][8]) {
  int lane = tid & 63, wv = tid >> 6;
  int l15 = lane & 15, quad = lane >> 4;
  #pragma unroll
  for (int kh = 0; kh < 2; ++kh) {
    bf16x8 af[2];
    #pragma unroll
    for (int pi = 0; pi < 2; ++pi)
      af[pi] = *reinterpret_cast<bf16x8*>(As + ((wv * 2 + pi) * 16 + l15) * SA + kh * 32 + quad * 8);
    #pragma unroll
    for (int ct = 0; ct < 8; ++ct) {
      bf16x8 bfr = *reinterpret_cast<bf16x8*>(Bs + (ct * 16 + l15) * SA + kh * 32 + quad * 8);
      acc[0][ct] = __builtin_amdgcn_mfma_f32_16x16x32_bf16(af[0], bfr, acc[0][ct], 0, 0, 0);
      acc[1][ct] = __builtin_amdgcn_mfma_f32_16x16x32_bf16(af[1], bfr, acc[1][ct], 0, 0, 0);
    }
  }
}

// ---------------- prep: gn (125) + tail (1) + biasG (1) + img_h partials (128) + M2T (16) + GT0 (8) ----------------
__global__ __launch_bounds__(256) void prep_k(
    const float* __restrict__ attributes, const float* __restrict__ att_g,
    ushort_t* __restrict__ gn_bf,
    const float* __restrict__ image_feats, const float* __restrict__ img_w,
    float* __restrict__ ihp,
    const float* __restrict__ proto_w, const float* __restrict__ slim_w,
    ushort_t* __restrict__ M2T, float* __restrict__ GT_part,
    const float* __restrict__ slim_b, const float* __restrict__ proto_b,
    float* __restrict__ biasG) {
  __shared__ ushort_t As[128 * SA];
  __shared__ ushort_t Bs[128 * SA];
  int b = blockIdx.x, tid = threadIdx.x;
  if (b < 125) {
    __shared__ float a_lds[8][316];
    __shared__ float red2[8][2];
    int h = tid & 127;
    int c0 = b * 8;
    for (int idx = tid; idx < 8 * 312; idx += 256) {
      int r = idx / 312;
      int k = idx - r * 312;
      a_lds[r][k] = attributes[(c0 + r) * 312 + k];
    }
    __syncthreads();
    float acc[8] = {0.f,0.f,0.f,0.f,0.f,0.f,0.f,0.f};
    #pragma unroll 2
    for (int k = 0; k < 312; k += 4) {
      float w0 = att_g[(k + 0) * 128 + h];
      float w1 = att_g[(k + 1) * 128 + h];
      float w2 = att_g[(k + 2) * 128 + h];
      float w3 = att_g[(k + 3) * 128 + h];
      #pragma unroll
      for (int r = 0; r < 8; ++r) {
        float4 a4 = *reinterpret_cast<const float4*>(&a_lds[r][k]);
        acc[r] += a4.x * w0 + a4.y * w1 + a4.z * w2 + a4.w * w3;
      }
    }
    int lane = tid & 63, wvid = (tid >> 6) & 1;
    #pragma unroll
    for (int r = 0; r < 8; ++r) {
      float v = acc[r] * acc[r];
      #pragma unroll
      for (int off = 32; off > 0; off >>= 1) v += __shfl_xor(v, off, 64);
      if (lane == 0) red2[r][wvid] = v;
    }
    __syncthreads();
    #pragma unroll
    for (int r = 0; r < 8; ++r) {
      float nrm = fmaxf(sqrtf(red2[r][0] + red2[r][1]), 1e-12f);
      gn_bf[(c0 + r) * 128 + h] = f2bf(acc[r] / nrm);
    }
    return;
  }
  if (b == 125) {               // zero gn_bf rows 1000..1007
    us4 z = {0, 0, 0, 0};
    *reinterpret_cast<us4*>(gn_bf + 1000 * 128 + tid * 4) = z;
    return;
  }
  if (b == 126) {               // biasG[h] = proto_b[h] + sum_n slim_b[n]*proto_w[312+n][h]
    int h = tid & 127;
    float acc = proto_b[h];
    for (int n = 0; n < 312; n += 4) {
      acc += slim_b[n + 0] * proto_w[(size_t)(312 + n) * 128 + h];
      acc += slim_b[n + 1] * proto_w[(size_t)(313 + n) * 128 + h];
      acc += slim_b[n + 2] * proto_w[(size_t)(314 + n) * 128 + h];
      acc += slim_b[n + 3] * proto_w[(size_t)(315 + n) * 128 + h];
    }
    if (tid < 128) biasG[h] = acc;
    return;
  }
  int lane = tid & 63, wv = tid >> 6;
  int l15 = lane & 15, quad = lane >> 4;
  f32x4 acc[2][8];
  #pragma unroll
  for (int i = 0; i < 2; ++i)
    #pragma unroll
    for (int j = 0; j < 8; ++j) acc[i][j] = f32x4{0.f, 0.f, 0.f, 0.f};

  if (b < 255) {                // img_h split-K partial: ihp[kc][r0..+128][0..128)
    int q = b - 127;
    int tile = q >> 3, kc = q & 7;
    int r0 = tile * 128, k0 = kc * 256;
    for (int s = 0; s < 4; ++s) {
      if (s) __syncthreads();
      stage_R(image_feats, 2048, r0, 2047, k0 + s * 64, 1 << 30, As, tid);
      stage_T(img_w, 128, k0 + s * 64, 2048, 0, Bs, tid);
      __syncthreads();
      mfma8(As, Bs, tid, acc);
    }
    float* Cp = ihp + (size_t)kc * 2048 * 128;
    #pragma unroll
    for (int pi = 0; pi < 2; ++pi)
      #pragma unroll
      for (int ct = 0; ct < 8; ++ct) {
        int col = ct * 16 + l15;
        #pragma unroll
        for (int r = 0; r < 4; ++r) {
          int row = r0 + (wv * 2 + pi) * 16 + quad * 4 + r;
          Cp[(size_t)row * 128 + col] = acc[pi][ct][r];
        }
      }
    return;
  }
  if (b < 271) {                // M2T[h][d] = sum_n proto_w[312+n][h] * slim_w[d][n]
    int c0 = (b - 255) * 128;
    for (int s = 0; s < 5; ++s) {
      if (s) __syncthreads();
      stage_T(proto_w, 128, 312 + s * 64, 624, 0, As, tid);
      stage_R(slim_w, 312, c0, 2047, s * 64, 312, Bs, tid);
      __syncthreads();
      mfma8(As, Bs, tid, acc);
    }
    #pragma unroll
    for (int pi = 0; pi < 2; ++pi)
      #pragma unroll
      for (int ct = 0; ct < 8; ++ct) {
        int col = c0 + ct * 16 + l15;
        #pragma unroll
        for (int r = 0; r < 4; ++r) {
          int row = (wv * 2 + pi) * 16 + quad * 4 + r;
          M2T[(size_t)row * 2048 + col] = f2bf(acc[pi][ct][r]);
        }
      }
    return;
  }
  {                             // GT0[h][j] = sum_n proto_w[n][h] * attributes[j][n]
    int j0 = (b - 271) * 128;
    for (int s = 0; s < 5; ++s) {
      if (s) __syncthreads();
      stage_T(proto_w, 128, s * 64, 312, 0, As, tid);
      stage_R(attributes, 312, j0, 999, s * 64, 312, Bs, tid);
      __syncthreads();
      mfma8(As, Bs, tid, acc);
    }
    #pragma unroll
    for (int pi = 0; pi < 2; ++pi)
      #pragma unroll
      for (int ct = 0; ct < 8; ++ct) {
        int col = j0 + ct * 16 + l15;
        #pragma unroll
        for (int r = 0; r < 4; ++r) {
          int row = (wv * 2 + pi) * 16 + quad * 4 + r;
          GT_part[(size_t)row * 1024 + col] = acc[pi][ct][r];
        }
      }
  }
}

// ---------------- red: img_h reduce (128) + GT chunks 1..4 partials (32) ----------------
__global__ __launch_bounds__(256) void red_k(
    const float* __restrict__ ihp, float* __restrict__ img_h,
    const ushort_t* __restrict__ M2T, const float* __restrict__ img_proto,
    float* __restrict__ GT_part) {
  __shared__ ushort_t As[128 * SA];
  __shared__ ushort_t Bs[128 * SA];
  int b = blockIdx.x, tid = threadIdx.x;
  if (b < 128) {                // img_h[r][h] = sum_{c<8} ihp[c][r][h]
    int t = b * 256 + tid;      // 0..32767
    size_t base = (size_t)t * 8;
    #pragma unroll
    for (int g = 0; g < 2; ++g) {
      float4 s = *reinterpret_cast<const float4*>(ihp + base + g * 4);
      #pragma unroll
      for (int c = 1; c < 8; ++c) {
        float4 v = *reinterpret_cast<const float4*>(ihp + (size_t)c * 262144 + base + g * 4);
        s.x += v.x; s.y += v.y; s.z += v.z; s.w += v.w;
      }
      *reinterpret_cast<float4*>(img_h + base + g * 4) = s;
    }
    return;
  }
  int q = b - 128;              // 0..31
  int jt = q >> 2, ch = q & 3;
  int j0 = jt * 128, k0 = ch * 512;
  f32x4 acc[2][8];
  #pragma unroll
  for (int i = 0; i < 2; ++i)
    #pragma unroll
    for (int j = 0; j < 8; ++j) acc[i][j] = f32x4{0.f, 0.f, 0.f, 0.f};
  for (int s = 0; s < 8; ++s) {
    if (s) __syncthreads();
    stage_Abf(M2T, 2048, k0 + s * 64, As, tid);
    stage_R(img_proto, 2048, j0, 999, k0 + s * 64, 1 << 30, Bs, tid);
    __syncthreads();
    mfma8(As, Bs, tid, acc);
  }
  int lane = tid & 63, wv = tid >> 6;
  int l15 = lane & 15, quad = lane >> 4;
  float* dst = GT_part + (size_t)(ch + 1) * 131072;
  #pragma unroll
  for (int pi = 0; pi < 2; ++pi)
    #pragma unroll
    for (int ct = 0; ct < 8; ++ct) {
      int col = j0 + ct * 16 + l15;
      #pragma unroll
      for (int r = 0; r < 4; ++r) {
        int row = (wv * 2 + pi) * 16 + quad * 4 + r;
        dst[(size_t)row * 1024 + col] = acc[pi][ct][r];
      }
    }
}

// ---------------- gtred: GT = bf16( sum_{c<5} GT_part[c] + biasG[h] ) ----------------
__global__ __launch_bounds__(256) void gtred_k(const float* __restrict__ GT_part,
                                               const float* __restrict__ biasG,
                                               ushort_t* __restrict__ GT) {
  int t = blockIdx.x * 256 + threadIdx.x;   // 0..8191
  size_t base = (size_t)t * 16;
  int row = (int)(base >> 10);
  float bg = biasG[row];
  #pragma unroll
  for (int g = 0; g < 4; ++g) {
    float4 s = *reinterpret_cast<const float4*>(GT_part + base + g * 4);
    #pragma unroll
    for (int c = 1; c < 5; ++c) {
      float4 v = *reinterpret_cast<const float4*>(GT_part + (size_t)c * 131072 + base + g * 4);
      s.x += v.x; s.y += v.y; s.z += v.z; s.w += v.w;
    }
    s.x += bg; s.y += bg; s.z += bg; s.w += bg;
    *reinterpret_cast<us4*>(GT + base + g * 4) = pack4(s);
  }
}

// ---------------- attn6: sim -> masked exp -> ph = (W@GT^T)/rsum ; 512 threads ----------------
__global__ __launch_bounds__(512) void attn6_k(
    const ushort_t* __restrict__ gn_bf, const ushort_t* __restrict__ GT,
    float* __restrict__ ph) {
  __shared__ ushort_t W[16 * SW];
  __shared__ float rsum[16];
  __shared__ int flags[63];
  int tid = threadIdx.x;
  int i0 = blockIdx.x * 16;
  int lane = tid & 63, wv = tid >> 6;       // wv 0..7
  int l15 = lane & 15, quad = lane >> 4;
  if (tid < 63) flags[tid] = 0;
  if (tid >= 64 && tid < 80) rsum[tid - 64] = 0.f;
  if (tid < 256) W[(tid >> 4) * SW + 1008 + (tid & 15)] = 0;   // zero k-pad cols 1008..1023
  __syncthreads();

  const ushort_t* abase = gn_bf + (size_t)(i0 + l15) * 128 + quad * 8;
  bf16x8 af0 = *reinterpret_cast<const bf16x8*>(abase);
  bf16x8 af1 = *reinterpret_cast<const bf16x8*>(abase + 32);
  bf16x8 af2 = *reinterpret_cast<const bf16x8*>(abase + 64);
  bf16x8 af3 = *reinterpret_cast<const bf16x8*>(abase + 96);
  float rs[4] = {0.f, 0.f, 0.f, 0.f};
  for (int jt = wv; jt < 63; jt += 8) {
    const ushort_t* bbase = gn_bf + (size_t)(jt * 16 + l15) * 128 + quad * 8;
    f32x4 d = {0.f, 0.f, 0.f, 0.f};
    d = __builtin_amdgcn_mfma_f32_16x16x32_bf16(af0, *reinterpret_cast<const bf16x8*>(bbase),      d, 0, 0, 0);
    d = __builtin_amdgcn_mfma_f32_16x16x32_bf16(af1, *reinterpret_cast<const bf16x8*>(bbase + 32), d, 0, 0, 0);
    d = __builtin_amdgcn_mfma_f32_16x16x32_bf16(af2, *reinterpret_cast<const bf16x8*>(bbase + 64), d, 0, 0, 0);
    d = __builtin_amdgcn_mfma_f32_16x16x32_bf16(af3, *reinterpret_cast<const bf16x8*>(bbase + 96), d, 0, 0, 0);
    int hot = 0;
    #pragma unroll
    for (int r = 0; r < 4; ++r) {
      float w = 0.f;
      if (d[r] > THRESH) { w = __expf(T_SOFT * (d[r] - 1.0f)); hot = 1; }
      ushort_t wb = f2bf(w);
      W[(quad * 4 + r) * SW + jt * 16 + l15] = wb;
      rs[r] += bf2f(wb);
    }
    if (hot) flags[jt] = 1;
  }
  #pragma unroll
  for (int r = 0; r < 4; ++r) {
    float v = rs[r];
    v += __shfl_xor(v, 1, 64); v += __shfl_xor(v, 2, 64);
    v += __shfl_xor(v, 4, 64); v += __shfl_xor(v, 8, 64);
    if (l15 == 0) atomicAdd(&rsum[quad * 4 + r], v);
  }
  __syncthreads();

  // phase 2: wave wv owns h-tile wv
  f32x4 acc2 = {0.f, 0.f, 0.f, 0.f};
  int h = wv * 16 + l15;
  for (int s = 0; s < 32; ++s) {
    int f = flags[2 * s] | ((2 * s + 1 < 63) ? flags[2 * s + 1] : 0);
    if (!f) continue;
    bf16x8 a = *reinterpret_cast<bf16x8*>(W + l15 * SW + s * 32 + quad * 8);
    bf16x8 bfr = *reinterpret_cast<const bf16x8*>(GT + (size_t)h * 1024 + s * 32 + quad * 8);
    acc2 = __builtin_amdgcn_mfma_f32_16x16x32_bf16(a, bfr, acc2, 0, 0, 0);
  }
  #pragma unroll
  for (int r = 0; r < 4; ++r) {
    int row = quad * 4 + r;
    int gi = i0 + row;
    float inv = 1.f / fmaxf(rsum[row], 1e-30f);
    if (gi < 1000) ph[(size_t)gi * 128 + h] = acc2[r] * inv;
  }
}

// ---------------- final: out[b,c] = fc_b + sum_h relu(img_h[b,h]+ph[c,h]) * fc_w[h] ----------------
// 64x64 tiles, 512 blocks, 256 threads (2 blocks/CU)
__global__ __launch_bounds__(256) void final_k(
    const float* __restrict__ img_h, const float* __restrict__ ph,
    const float* __restrict__ fc_w, const float* __restrict__ fc_b,
    float* __restrict__ out) {
  __shared__ float ih[64][132];
  __shared__ float ps[64][132];
  __shared__ float ws_[128];
  int tid = threadIdx.x;
  int b0 = blockIdx.x * 64;
  int c0 = blockIdx.y * 64;
  for (int idx = tid; idx < 2048; idx += 256) {
    int row = idx >> 5, c4 = (idx & 31) * 4;
    float4 v = *reinterpret_cast<const float4*>(img_h + (size_t)(b0 + row) * 128 + c4);
    *reinterpret_cast<float4*>(&ih[row][c4]) = v;
  }
  for (int idx = tid; idx < 2048; idx += 256) {
    int row = idx >> 5, c4 = (idx & 31) * 4;
    int c = c0 + row;
    float4 v = make_float4(0.f, 0.f, 0.f, 0.f);
    if (c < 1000) v = *reinterpret_cast<const float4*>(ph + (size_t)c * 128 + c4);
    *reinterpret_cast<float4*>(&ps[row][c4]) = v;
  }
  if (tid < 128) ws_[tid] = fc_w[tid];
  __syncthreads();
  int tx = tid & 15, ty = tid >> 4;   // ty 0..15 -> 4 b-rows; tx -> 4 c-cols
  f32x2 acc[4][4] = {};
  const f32x2 zero2 = {0.f, 0.f};
  for (int h = 0; h < 128; h += 4) {
    float4 w4 = *reinterpret_cast<float4*>(&ws_[h]);
    f32x2 wlo = {w4.x, w4.y}, whi = {w4.z, w4.w};
    float4 a4[4], p4[4];
    #pragma unroll
    for (int i = 0; i < 4; ++i) a4[i] = *reinterpret_cast<float4*>(&ih[ty * 4 + i][h]);
    #pragma unroll
    for (int j = 0; j < 4; ++j) p4[j] = *reinterpret_cast<float4*>(&ps[tx * 4 + j][h]);
    #pragma unroll
    for (int i = 0; i < 4; ++i) {
      f32x2 alo = {a4[i].x, a4[i].y}, ahi = {a4[i].z, a4[i].w};
      #pragma unroll
      for (int j = 0; j < 4; ++j) {
        f32x2 plo = {p4[j].x, p4[j].y}, phi = {p4[j].z, p4[j].w};
        f32x2 t0 = __builtin_elementwise_max(alo + plo, zero2);
        f32x2 t1 = __builtin_elementwise_max(ahi + phi, zero2);
        acc[i][j] = acc[i][j] + t0 * wlo;
        acc[i][j] = acc[i][j] + t1 * whi;
      }
    }
  }
  float fb = fc_b[0];
  #pragma unroll
  for (int i = 0; i < 4; ++i) {
    int b = b0 + ty * 4 + i;
    int c = c0 + tx * 4;
    if (c < 1000) {
      float4 v = make_float4(acc[i][0].x + acc[i][0].y + fb, acc[i][1].x + acc[i][1].y + fb,
                             acc[i][2].x + acc[i][2].y + fb, acc[i][3].x + acc[i][3].y + fb);
      *reinterpret_cast<float4*>(out + (size_t)b * 1000 + c) = v;
    }
  }
}

extern "C" void kernel_launch(void* const* d_in, const int* in_sizes, int n_in,
                              void* d_out, int out_size, void* d_ws, size_t ws_size,
                              hipStream_t stream) {
  const float* image_feats = (const float*)d_in[0];   // [2048,2048]
  const float* img_proto   = (const float*)d_in[1];   // [1000,2048]
  const float* attributes  = (const float*)d_in[2];   // [1000,312]
  const float* att_g   = (const float*)d_in[4];       // [312,128]
  const float* slim_w  = (const float*)d_in[5];       // [2048,312]
  const float* slim_b  = (const float*)d_in[6];       // [312]
  const float* img_w   = (const float*)d_in[7];       // [2048,128]
  const float* proto_w = (const float*)d_in[8];       // [624,128]
  const float* proto_b = (const float*)d_in[9];       // [1,128]
  const float* fc_w    = (const float*)d_in[10];      // [128,1]
  const float* fc_b    = (const float*)d_in[11];      // [1]
  float* out = (float*)d_out;                         // [2048,1000]

  char* ws = (char*)d_ws;
  size_t o = 0;
  auto alloc = [&](size_t bytes) { size_t r = o; o += (bytes + 255) & ~(size_t)255; return r; };
  ushort_t* gn_bf   = (ushort_t*)(ws + alloc(1008ull * 128 * 2));   // normalized g bf16, tail zero
  ushort_t* M2T     = (ushort_t*)(ws + alloc(128ull * 2048 * 2));   // (slim_w @ proto_w2)^T bf16
  ushort_t* GT      = (ushort_t*)(ws + alloc(128ull * 1024 * 2));   // Gn^T + biasG, bf16
  float* biasG     = (float*)(ws + alloc(128ull * 4));              // slim_b@proto_w2 + proto_b
  float* ihp       = (float*)(ws + alloc(8ull * 2048 * 128 * 4));   // img_h split-K partials
  float* GT_part   = (float*)(ws + alloc(5ull * 128 * 1024 * 4));   // GT split-K partials
  float* img_h     = (float*)(ws + alloc(2048ull * 128 * 4));
  float* ph        = (float*)(ws + alloc(1000ull * 128 * 4));

  // gn (125) + tail (1) + biasG (1) + img_h partials (128) + M2T (16) + GT0 (8)
  prep_k<<<279, 256, 0, stream>>>(attributes, att_g, gn_bf,
                                  image_feats, img_w, ihp,
                                  proto_w, slim_w, M2T, GT_part,
                                  slim_b, proto_b, biasG);

  // img_h reduce (128) + GT chunks 1..4 (32)
  red_k<<<160, 256, 0, stream>>>(ihp, img_h, M2T, img_proto, GT_part);

  // GT reduce + bias fold
  gtred_k<<<32, 256, 0, stream>>>(GT_part, biasG, GT);

  // sim -> masked exp -> ph
  attn6_k<<<63, 512, 0, stream>>>(gn_bf, GT, ph);

  final_k<<<dim3(32, 16), 256, 0, stream>>>(img_h, ph, fc_w, fc_b, out);
}